// Round 12
// baseline (239.384 us; speedup 1.0000x reference)
//
#include <hip/hip_runtime.h>
#include <math.h>

// Problem constants
#define BB 8
#define NN 8192
#define SS 1024
#define NS 32      // nsample
#define DD 64      // point feature channels
#define C1 128     // layer-1 out
#define C2 256     // layer-2 out
#define R2 0.04f   // radius^2
#define CPB 4      // centers per block in fused2

using bf16x8 = __attribute__((ext_vector_type(8))) short;
using f32x4  = __attribute__((ext_vector_type(4))) float;

// fast silu: x * rcp(1 + exp2(-x*log2e)) — 2 trans + 3 VALU
__device__ __forceinline__ float rcp_f(float v) {
    float r; asm("v_rcp_f32 %0, %1" : "=v"(r) : "v"(v)); return r;
}
__device__ __forceinline__ float exp2_f(float v) {
    float r; asm("v_exp_f32 %0, %1" : "=v"(r) : "v"(v)); return r;
}
__device__ __forceinline__ float silu_f(float x) {
    return x * rcp_f(1.0f + exp2_f(x * -1.44269504088896f));
}
// f32 -> bf16 (RTN-even), returns in low 16 bits
__device__ __forceinline__ unsigned int f2bf(float f) {
    unsigned int u = __float_as_uint(f);
    u += 0x7fffu + ((u >> 16) & 1u);
    return u >> 16;
}
__device__ __forceinline__ float bfl(unsigned int u) { return __uint_as_float(u << 16); }
__device__ __forceinline__ float bfh(unsigned int u) { return __uint_as_float(u & 0xffff0000u); }

// build one bf16x8 B-fragment from 8 consecutive f32 (row-major weight slice)
__device__ __forceinline__ bf16x8 frag8(const float* __restrict__ src) {
    uint4 u = make_uint4(f2bf(src[0]) | (f2bf(src[1]) << 16),
                         f2bf(src[2]) | (f2bf(src[3]) << 16),
                         f2bf(src[4]) | (f2bf(src[5]) << 16),
                         f2bf(src[6]) | (f2bf(src[7]) << 16));
    return *(bf16x8*)&u;
}

// ---------------------------------------------------------------------------
// K1: query_ball_point, dual-chunk + 1-deep prefetch. (UNCHANGED from r10 —
// verified; measured-neutral vs r6 but harmless.)
// ---------------------------------------------------------------------------
__global__ __launch_bounds__(256) void qbp_kernel(const float* __restrict__ xyz,
                                                  int* __restrict__ idx_ws) {
    int gwave = (blockIdx.x * blockDim.x + threadIdx.x) >> 6;
    int lane  = threadIdx.x & 63;
    int b = gwave >> 10;
    int s = gwave & (SS - 1);
    const float* x = xyz + (size_t)b * 2 * NN;
    const float* y = x + NN;
    float cx = x[s], cy = y[s];
    float cs = __fadd_rn(__fmul_rn(cx, cx), __fmul_rn(cy, cy));
    int* ob = idx_ws + ((size_t)(b * SS + s)) * NS;

    float pxA = x[lane],      pyA = y[lane];
    float pxB = x[64 + lane], pyB = y[64 + lane];

    int written = 0;
    int first = -1;
    for (int base = 0; base < NN && written < NS; base += 128) {
        int jA2 = base + 128 + lane;      if (jA2 >= NN) jA2 = NN - 1;
        int jB2 = base + 192 + lane;      if (jB2 >= NN) jB2 = NN - 1;
        float nxA = x[jA2], nyA = y[jA2];
        float nxB = x[jB2], nyB = y[jB2];

        float ppA = __fadd_rn(__fmul_rn(pxA, pxA), __fmul_rn(pyA, pyA));
        float eA  = __fadd_rn(__fmul_rn(cx, pxA), __fmul_rn(cy, pyA));
        float dA  = __fadd_rn(__fadd_rn(__fmul_rn(-2.0f, eA), cs), ppA);
        float ppB = __fadd_rn(__fmul_rn(pxB, pxB), __fmul_rn(pyB, pyB));
        float eB  = __fadd_rn(__fmul_rn(cx, pxB), __fmul_rn(cy, pyB));
        float dB  = __fadd_rn(__fadd_rn(__fmul_rn(-2.0f, eB), cs), ppB);
        bool inA = !(dA > R2);
        bool inB = !(dB > R2);
        unsigned long long mA = __ballot(inA);
        unsigned long long mB = __ballot(inB);
        if (first < 0) {
            if (mA)      first = base + (__ffsll(mA) - 1);
            else if (mB) first = base + 64 + (__ffsll(mB) - 1);
        }
        unsigned long long below = (1ull << lane) - 1ull;
        int posA = __popcll(mA & below);
        if (inA && written + posA < NS) ob[written + posA] = base + lane;
        int wA = written + __popcll(mA);
        int posB = __popcll(mB & below);
        if (inB && wA + posB < NS) ob[wA + posB] = base + 64 + lane;
        written = wA + __popcll(mB);
        if (written > NS) written = NS;

        pxA = nxA; pyA = nyA; pxB = nxB; pyB = nyB;
    }
    if (lane >= written && lane < NS) ob[lane] = first;
}

// ---------------------------------------------------------------------------
// K2: P1 GEMM via MFMA. r11: W1 B-fragments built directly from global W1
// (identical index map + f2bf as the old pack_kernel — bit-identical values).
// ---------------------------------------------------------------------------
__global__ __launch_bounds__(256) void p1g_kernel(const float* __restrict__ points,
                                                  const float* __restrict__ W1,
                                                  const float* __restrict__ b1,
                                                  unsigned short* __restrict__ P1) {
    __shared__ __align__(16) char lds[34816];
    const int t = threadIdx.x;
    const int w = t >> 6, l = t & 63;
    const int bidx = blockIdx.x;               // BB * (NN/128) = 512
    const int b  = bidx >> 6;
    const int j0 = (bidx & 63) << 7;

    // B-fragments direct from W1 (skip 2 xy cols): o=nt*16+(l&15), c0=kb*32+(l>>4)*8
    bf16x8 bfr[8][2];
    #pragma unroll
    for (int nt = 0; nt < 8; ++nt)
        #pragma unroll
        for (int kb = 0; kb < 2; ++kb) {
            int o  = nt * 16 + (l & 15);
            int c0 = kb * 32 + ((l >> 4) << 3);
            bfr[nt][kb] = frag8(W1 + (size_t)o * 66 + 2 + c0);
        }
    float b1v[8];
    #pragma unroll
    for (int nt = 0; nt < 8; ++nt) b1v[nt] = b1[nt * 16 + (l & 15)];

    {
        const float* pb = points + (size_t)b * DD * NN + j0;
        int jj0 = (t & 31) * 4;
        #pragma unroll
        for (int i = 0; i < 4; ++i) {
            int c = 2 * ((t >> 5) + i * 8);
            float4 q0 = *(const float4*)(pb + (size_t)c * NN + jj0);
            float4 q1 = *(const float4*)(pb + (size_t)(c + 1) * NN + jj0);
            float a0[4] = {q0.x, q0.y, q0.z, q0.w};
            float a1[4] = {q1.x, q1.y, q1.z, q1.w};
            #pragma unroll
            for (int d = 0; d < 4; ++d) {
                int jj = jj0 + d;
                unsigned int u = f2bf(a0[d]) | (f2bf(a1[d]) << 16);
                unsigned int addr = ((unsigned)(jj * 128 + c * 2))
                                    ^ ((unsigned)((((jj & 7) ^ ((jj >> 2) & 7)) << 4)));
                *(unsigned int*)(lds + addr) = u;
            }
        }
    }
    __syncthreads();

    bf16x8 afr[2][2];
    #pragma unroll
    for (int mt = 0; mt < 2; ++mt)
        #pragma unroll
        for (int kb = 0; kb < 2; ++kb) {
            int jg = w * 32 + mt * 16 + (l & 15);
            unsigned int addr = ((unsigned)(jg * 128 + kb * 64 + ((l >> 4) << 4)))
                                ^ ((unsigned)((((jg & 7) ^ ((jg >> 2) & 7)) << 4)));
            afr[mt][kb] = *(const bf16x8*)(lds + addr);
        }
    __syncthreads();

    f32x4 acc[2][8];
    #pragma unroll
    for (int mt = 0; mt < 2; ++mt)
        #pragma unroll
        for (int nt = 0; nt < 8; ++nt) {
            f32x4 z4 = {0.0f, 0.0f, 0.0f, 0.0f};
            acc[mt][nt] = z4;
        }
    #pragma unroll
    for (int kb = 0; kb < 2; ++kb)
        #pragma unroll
        for (int mt = 0; mt < 2; ++mt)
            #pragma unroll
            for (int nt = 0; nt < 8; ++nt)
                acc[mt][nt] = __builtin_amdgcn_mfma_f32_16x16x32_bf16(
                    afr[mt][kb], bfr[nt][kb], acc[mt][nt], 0, 0, 0);

    #pragma unroll
    for (int mt = 0; mt < 2; ++mt)
        #pragma unroll
        for (int nt = 0; nt < 8; ++nt) {
            int row0 = w * 32 + mt * 16 + ((l >> 4) << 2);
            int col  = nt * 16 + (l & 15);
            #pragma unroll
            for (int r = 0; r < 4; ++r) {
                float v = acc[mt][nt][r] + b1v[nt];
                *(unsigned short*)(lds + (size_t)(row0 + r) * 272 + col * 2) =
                    (unsigned short)f2bf(v);
            }
        }
    __syncthreads();

    {
        int row = t >> 1, half = t & 1;
        const char* src = lds + (size_t)row * 272 + half * 128;
        unsigned short* dst = P1 + ((size_t)(b * NN + j0 + row)) * C1 + half * 64;
        #pragma unroll
        for (int i = 0; i < 8; ++i)
            *(uint4*)(dst + i * 8) = *(const uint4*)(src + i * 16);
    }
}

// ---------------------------------------------------------------------------
// K3: fused gather + layer1 xy-term + silu + MFMA layer2 + silu + mean.
// r11: W2 B-fragments built directly from global W2 (pack kernel removed);
// kb-outer MFMA loop with just-in-time A-fragment loads (VGPR cut: afr 32->8).
// Everything else identical to the verified r10 kernel.
// ---------------------------------------------------------------------------
__global__ __launch_bounds__(256) void fused2_kernel(const float* __restrict__ xyz,
                                                     const float* __restrict__ W1,
                                                     const float* __restrict__ W2,
                                                     const float* __restrict__ b2,
                                                     const unsigned short* __restrict__ P1,
                                                     const int* __restrict__ idx_ws,
                                                     float* __restrict__ tmp) {
    __shared__ __align__(16) unsigned short H1s[2][NS * C1];   // 2 x 8 KB
    __shared__ int   idxs[CPB][NS];
    __shared__ float dxs[CPB][NS], dys[CPB][NS];
    __shared__ float w1xy[C1][2];

    const int t = threadIdx.x;
    const int w = t >> 6, l = t & 63;
    const int gc0 = blockIdx.x * CPB;
    const int b   = gc0 >> 10;             // CPB divides 1024: block-uniform

    if (t < C1) {
        w1xy[t][0] = W1[(size_t)t * 66 + 0];
        w1xy[t][1] = W1[(size_t)t * 66 + 1];
    }
    if (t < CPB * NS) {                    // 128 threads stage idx/dx/dy
        int ci = t >> 5, kk = t & 31;
        int gc = gc0 + ci;
        int s = gc & (SS - 1);
        const float* x = xyz + (size_t)b * 2 * NN;
        const float* y = x + NN;
        int j = idx_ws[(size_t)gc * NS + kk];
        idxs[ci][kk] = j;
        dxs[ci][kk] = x[j] - x[s];
        dys[ci][kk] = y[j] - y[s];
    }

    // W2 B-fragments direct from global (same map+f2bf as old pack kernel):
    // o = nt*16+(l&15), c0 = kb*32+(l>>4)*8, nt = w*4+ntl
    bf16x8 bfr[4][4];
    #pragma unroll
    for (int kb = 0; kb < 4; ++kb)
        #pragma unroll
        for (int ntl = 0; ntl < 4; ++ntl) {
            int o  = (w * 4 + ntl) * 16 + (l & 15);
            int c0 = kb * 32 + ((l >> 4) << 3);
            bfr[ntl][kb] = frag8(W2 + (size_t)o * C1 + c0);
        }
    float b2v[4];
    #pragma unroll
    for (int ntl = 0; ntl < 4; ++ntl) b2v[ntl] = b2[w * 64 + ntl * 16 + (l & 15)];

    __syncthreads();

    // --- loop-invariant per-thread state, hoisted ---
    const int k = t >> 3, cb = t & 7;      // staging roles: sample, c-block
    float wx[16], wy[16];
    #pragma unroll
    for (int i = 0; i < 16; ++i) {
        wx[i] = w1xy[cb * 16 + i][0];
        wy[i] = w1xy[cb * 16 + i][1];
    }
    const unsigned int swz = (unsigned)((k & 7) << 4);
    const unsigned int sa0 = ((unsigned)(k * 256 + cb * 32)) ^ swz;
    const unsigned int sa1 = ((unsigned)(k * 256 + cb * 32 + 16)) ^ swz;
    unsigned int afr_addr[2][4];
    #pragma unroll
    for (int mt = 0; mt < 2; ++mt)
        #pragma unroll
        for (int kb = 0; kb < 4; ++kb) {
            int m = mt * 16 + (l & 15);
            afr_addr[mt][kb] = ((unsigned)(m * 256 + kb * 64 + ((l >> 4) << 4)))
                               ^ ((unsigned)((m & 7) << 4));
        }
    const unsigned short* P1b = P1 + (size_t)b * NN * C1 + cb * 16;

    // --- software-pipelined center loop: ci=-1 primes buf0 ---
    for (int ci = -1; ci < CPB; ++ci) {
        const bool have = (ci + 1 < CPB);

        // phase 1: issue next center's gather (latency hidden under phase 2)
        uint4 q0, q1; float dx = 0.0f, dy = 0.0f;
        if (have) {
            int j = idxs[ci + 1][k];
            dx = dxs[ci + 1][k]; dy = dys[ci + 1][k];
            const uint4* pr = (const uint4*)(P1b + (size_t)j * C1);
            q0 = pr[0]; q1 = pr[1];
        }

        // phase 2: MFMA + epilogue for current center from buf[ci&1]
        if (ci >= 0) {
            const char* bufr = (const char*)H1s[ci & 1];
            f32x4 acc[2][4];
            #pragma unroll
            for (int mt = 0; mt < 2; ++mt)
                #pragma unroll
                for (int ntl = 0; ntl < 4; ++ntl) {
                    f32x4 z4 = {0.0f, 0.0f, 0.0f, 0.0f};
                    acc[mt][ntl] = z4;
                }
            #pragma unroll 1
            for (int kb = 0; kb < 4; ++kb) {       // kb-outer: afr JIT (8 VGPR live)
                bf16x8 a0 = *(const bf16x8*)(bufr + afr_addr[0][kb]);
                bf16x8 a1 = *(const bf16x8*)(bufr + afr_addr[1][kb]);
                #pragma unroll
                for (int ntl = 0; ntl < 4; ++ntl) {
                    acc[0][ntl] = __builtin_amdgcn_mfma_f32_16x16x32_bf16(
                        a0, bfr[ntl][kb], acc[0][ntl], 0, 0, 0);
                    acc[1][ntl] = __builtin_amdgcn_mfma_f32_16x16x32_bf16(
                        a1, bfr[ntl][kb], acc[1][ntl], 0, 0, 0);
                }
            }
            float po[4];
            #pragma unroll
            for (int ntl = 0; ntl < 4; ++ntl) {
                float sum = 0.0f;
                #pragma unroll
                for (int mt = 0; mt < 2; ++mt)
                    #pragma unroll
                    for (int r = 0; r < 4; ++r)
                        sum += silu_f(acc[mt][ntl][r] + b2v[ntl]);
                sum += __shfl_xor(sum, 16);
                sum += __shfl_xor(sum, 32);
                po[ntl] = sum * (1.0f / 32.0f);
            }
            if (l < 16) {
                int gc = gc0 + ci;
                #pragma unroll
                for (int ntl = 0; ntl < 4; ++ntl)
                    tmp[(size_t)gc * C2 + w * 64 + ntl * 16 + l] = po[ntl];
            }
        }

        // phase 3: silu + pack + LDS write for next center into buf[(ci+1)&1]
        if (have) {
            float hv[16];
            hv[0]  = bfl(q0.x); hv[1]  = bfh(q0.x);
            hv[2]  = bfl(q0.y); hv[3]  = bfh(q0.y);
            hv[4]  = bfl(q0.z); hv[5]  = bfh(q0.z);
            hv[6]  = bfl(q0.w); hv[7]  = bfh(q0.w);
            hv[8]  = bfl(q1.x); hv[9]  = bfh(q1.x);
            hv[10] = bfl(q1.y); hv[11] = bfh(q1.y);
            hv[12] = bfl(q1.z); hv[13] = bfh(q1.z);
            hv[14] = bfl(q1.w); hv[15] = bfh(q1.w);
            #pragma unroll
            for (int i = 0; i < 16; ++i) {
                float v = hv[i] + wx[i] * dx + wy[i] * dy;
                hv[i] = silu_f(v);
            }
            unsigned int up[8];
            #pragma unroll
            for (int q = 0; q < 8; ++q)
                up[q] = f2bf(hv[2 * q]) | (f2bf(hv[2 * q + 1]) << 16);
            char* bufw = (char*)H1s[(ci + 1) & 1];
            *(uint4*)(bufw + sa0) = make_uint4(up[0], up[1], up[2], up[3]);
            *(uint4*)(bufw + sa1) = make_uint4(up[4], up[5], up[6], up[7]);
        }
        __syncthreads();
    }
}

// ---------------------------------------------------------------------------
// K4: transpose tmp[b][s][o] -> out[b][o][s]. (UNCHANGED.)
// ---------------------------------------------------------------------------
__global__ __launch_bounds__(256) void transpose_kernel(const float* __restrict__ tmp,
                                                        float* __restrict__ out) {
    __shared__ float tile[32][33];
    int bid = blockIdx.x;
    int b  = bid >> 8;
    int r  = bid & 255;
    int s0 = (r >> 3) << 5;
    int o0 = (r & 7) << 5;
    int t = threadIdx.x;
    int c = t & 31, rr = t >> 5;
    const float* tb = tmp + (size_t)b * SS * C2;
    #pragma unroll
    for (int i = 0; i < 4; ++i) {
        int row = rr + i * 8;
        tile[row][c] = tb[(size_t)(s0 + row) * C2 + o0 + c];
    }
    __syncthreads();
    float* ob = out + (size_t)b * C2 * SS;
    #pragma unroll
    for (int i = 0; i < 4; ++i) {
        int row = rr + i * 8;
        ob[(size_t)(o0 + row) * SS + s0 + c] = tile[c][row];
    }
}

// ---------------------------------------------------------------------------
extern "C" void kernel_launch(void* const* d_in, const int* in_sizes, int n_in,
                              void* d_out, int out_size, void* d_ws, size_t ws_size,
                              hipStream_t stream) {
    const float* xyz    = (const float*)d_in[0];
    const float* points = (const float*)d_in[1];
    const float* W1     = (const float*)d_in[2];
    const float* b1     = (const float*)d_in[3];
    const float* W2     = (const float*)d_in[4];
    const float* b2     = (const float*)d_in[5];
    float* out = (float*)d_out;

    // workspace layout (total ~26.2 MB; r5-r10 passes prove ws >= 34.55 MB):
    //   idx : 1 MB    (offset 0)
    //   P1  : 16.8 MB (bf16)
    //   tmp : 8.4 MB  (f32 [b][s][o])
    const size_t OFF_P1  = (size_t)BB * SS * NS * sizeof(int);
    const size_t OFF_TMP = OFF_P1 + (size_t)BB * NN * C1 * sizeof(unsigned short);

    int*            idx = (int*)d_ws;
    unsigned short* P1  = (unsigned short*)((char*)d_ws + OFF_P1);
    float*          tmp = (float*)((char*)d_ws + OFF_TMP);

    qbp_kernel   <<<BB * SS / 4,     256, 0, stream>>>(xyz, idx);
    p1g_kernel   <<<BB * (NN / 128), 256, 0, stream>>>(points, W1, b1, P1);
    fused2_kernel<<<BB * SS / CPB,   256, 0, stream>>>(xyz, W1, W2, b2, P1, idx, tmp);
    transpose_kernel<<<BB * (SS / 32) * (C2 / 32), 256, 0, stream>>>(tmp, out);
}

// Round 13
// 181.962 us; speedup vs baseline: 1.3156x; 1.3156x over previous
//
#include <hip/hip_runtime.h>
#include <math.h>

// Problem constants
#define BB 8
#define NN 8192
#define SS 1024
#define NS 32      // nsample
#define DD 64      // point feature channels
#define C1 128     // layer-1 out
#define C2 256     // layer-2 out
#define R2 0.04f   // radius^2
#define CPB 4      // centers per block in fused2

using bf16x8 = __attribute__((ext_vector_type(8))) short;
using f32x4  = __attribute__((ext_vector_type(4))) float;

// fast silu: x * rcp(1 + exp2(-x*log2e)) — 2 trans + 3 VALU
__device__ __forceinline__ float rcp_f(float v) {
    float r; asm("v_rcp_f32 %0, %1" : "=v"(r) : "v"(v)); return r;
}
__device__ __forceinline__ float exp2_f(float v) {
    float r; asm("v_exp_f32 %0, %1" : "=v"(r) : "v"(v)); return r;
}
__device__ __forceinline__ float silu_f(float x) {
    return x * rcp_f(1.0f + exp2_f(x * -1.44269504088896f));
}
// f32 -> bf16 (RTN-even), returns in low 16 bits
__device__ __forceinline__ unsigned int f2bf(float f) {
    unsigned int u = __float_as_uint(f);
    u += 0x7fffu + ((u >> 16) & 1u);
    return u >> 16;
}
__device__ __forceinline__ float bfl(unsigned int u) { return __uint_as_float(u << 16); }
__device__ __forceinline__ float bfh(unsigned int u) { return __uint_as_float(u & 0xffff0000u); }

// build one bf16x8 B-fragment from 8 consecutive f32 (row-major weight slice)
__device__ __forceinline__ bf16x8 frag8(const float* __restrict__ src) {
    uint4 u = make_uint4(f2bf(src[0]) | (f2bf(src[1]) << 16),
                         f2bf(src[2]) | (f2bf(src[3]) << 16),
                         f2bf(src[4]) | (f2bf(src[5]) << 16),
                         f2bf(src[6]) | (f2bf(src[7]) << 16));
    return *(bf16x8*)&u;
}

// ---------------------------------------------------------------------------
// K1: query_ball_point, dual-chunk + 1-deep prefetch. (UNCHANGED — verified.)
// ---------------------------------------------------------------------------
__global__ __launch_bounds__(256) void qbp_kernel(const float* __restrict__ xyz,
                                                  int* __restrict__ idx_ws) {
    int gwave = (blockIdx.x * blockDim.x + threadIdx.x) >> 6;
    int lane  = threadIdx.x & 63;
    int b = gwave >> 10;
    int s = gwave & (SS - 1);
    const float* x = xyz + (size_t)b * 2 * NN;
    const float* y = x + NN;
    float cx = x[s], cy = y[s];
    float cs = __fadd_rn(__fmul_rn(cx, cx), __fmul_rn(cy, cy));
    int* ob = idx_ws + ((size_t)(b * SS + s)) * NS;

    float pxA = x[lane],      pyA = y[lane];
    float pxB = x[64 + lane], pyB = y[64 + lane];

    int written = 0;
    int first = -1;
    for (int base = 0; base < NN && written < NS; base += 128) {
        int jA2 = base + 128 + lane;      if (jA2 >= NN) jA2 = NN - 1;
        int jB2 = base + 192 + lane;      if (jB2 >= NN) jB2 = NN - 1;
        float nxA = x[jA2], nyA = y[jA2];
        float nxB = x[jB2], nyB = y[jB2];

        float ppA = __fadd_rn(__fmul_rn(pxA, pxA), __fmul_rn(pyA, pyA));
        float eA  = __fadd_rn(__fmul_rn(cx, pxA), __fmul_rn(cy, pyA));
        float dA  = __fadd_rn(__fadd_rn(__fmul_rn(-2.0f, eA), cs), ppA);
        float ppB = __fadd_rn(__fmul_rn(pxB, pxB), __fmul_rn(pyB, pyB));
        float eB  = __fadd_rn(__fmul_rn(cx, pxB), __fmul_rn(cy, pyB));
        float dB  = __fadd_rn(__fadd_rn(__fmul_rn(-2.0f, eB), cs), ppB);
        bool inA = !(dA > R2);
        bool inB = !(dB > R2);
        unsigned long long mA = __ballot(inA);
        unsigned long long mB = __ballot(inB);
        if (first < 0) {
            if (mA)      first = base + (__ffsll(mA) - 1);
            else if (mB) first = base + 64 + (__ffsll(mB) - 1);
        }
        unsigned long long below = (1ull << lane) - 1ull;
        int posA = __popcll(mA & below);
        if (inA && written + posA < NS) ob[written + posA] = base + lane;
        int wA = written + __popcll(mA);
        int posB = __popcll(mB & below);
        if (inB && wA + posB < NS) ob[wA + posB] = base + 64 + lane;
        written = wA + __popcll(mB);
        if (written > NS) written = NS;

        pxA = nxA; pyA = nyA; pxB = nxB; pyB = nyB;
    }
    if (lane >= written && lane < NS) ob[lane] = first;
}

// ---------------------------------------------------------------------------
// K2: P1 GEMM via MFMA, W1 B-fragments direct from global. (UNCHANGED r12 —
// verified PASS; all fragment indices compile-time static.)
// ---------------------------------------------------------------------------
__global__ __launch_bounds__(256) void p1g_kernel(const float* __restrict__ points,
                                                  const float* __restrict__ W1,
                                                  const float* __restrict__ b1,
                                                  unsigned short* __restrict__ P1) {
    __shared__ __align__(16) char lds[34816];
    const int t = threadIdx.x;
    const int w = t >> 6, l = t & 63;
    const int bidx = blockIdx.x;               // BB * (NN/128) = 512
    const int b  = bidx >> 6;
    const int j0 = (bidx & 63) << 7;

    bf16x8 bfr[8][2];
    #pragma unroll
    for (int nt = 0; nt < 8; ++nt)
        #pragma unroll
        for (int kb = 0; kb < 2; ++kb) {
            int o  = nt * 16 + (l & 15);
            int c0 = kb * 32 + ((l >> 4) << 3);
            bfr[nt][kb] = frag8(W1 + (size_t)o * 66 + 2 + c0);
        }
    float b1v[8];
    #pragma unroll
    for (int nt = 0; nt < 8; ++nt) b1v[nt] = b1[nt * 16 + (l & 15)];

    {
        const float* pb = points + (size_t)b * DD * NN + j0;
        int jj0 = (t & 31) * 4;
        #pragma unroll
        for (int i = 0; i < 4; ++i) {
            int c = 2 * ((t >> 5) + i * 8);
            float4 q0 = *(const float4*)(pb + (size_t)c * NN + jj0);
            float4 q1 = *(const float4*)(pb + (size_t)(c + 1) * NN + jj0);
            float a0[4] = {q0.x, q0.y, q0.z, q0.w};
            float a1[4] = {q1.x, q1.y, q1.z, q1.w};
            #pragma unroll
            for (int d = 0; d < 4; ++d) {
                int jj = jj0 + d;
                unsigned int u = f2bf(a0[d]) | (f2bf(a1[d]) << 16);
                unsigned int addr = ((unsigned)(jj * 128 + c * 2))
                                    ^ ((unsigned)((((jj & 7) ^ ((jj >> 2) & 7)) << 4)));
                *(unsigned int*)(lds + addr) = u;
            }
        }
    }
    __syncthreads();

    bf16x8 afr[2][2];
    #pragma unroll
    for (int mt = 0; mt < 2; ++mt)
        #pragma unroll
        for (int kb = 0; kb < 2; ++kb) {
            int jg = w * 32 + mt * 16 + (l & 15);
            unsigned int addr = ((unsigned)(jg * 128 + kb * 64 + ((l >> 4) << 4)))
                                ^ ((unsigned)((((jg & 7) ^ ((jg >> 2) & 7)) << 4)));
            afr[mt][kb] = *(const bf16x8*)(lds + addr);
        }
    __syncthreads();

    f32x4 acc[2][8];
    #pragma unroll
    for (int mt = 0; mt < 2; ++mt)
        #pragma unroll
        for (int nt = 0; nt < 8; ++nt) {
            f32x4 z4 = {0.0f, 0.0f, 0.0f, 0.0f};
            acc[mt][nt] = z4;
        }
    #pragma unroll
    for (int kb = 0; kb < 2; ++kb)
        #pragma unroll
        for (int mt = 0; mt < 2; ++mt)
            #pragma unroll
            for (int nt = 0; nt < 8; ++nt)
                acc[mt][nt] = __builtin_amdgcn_mfma_f32_16x16x32_bf16(
                    afr[mt][kb], bfr[nt][kb], acc[mt][nt], 0, 0, 0);

    #pragma unroll
    for (int mt = 0; mt < 2; ++mt)
        #pragma unroll
        for (int nt = 0; nt < 8; ++nt) {
            int row0 = w * 32 + mt * 16 + ((l >> 4) << 2);
            int col  = nt * 16 + (l & 15);
            #pragma unroll
            for (int r = 0; r < 4; ++r) {
                float v = acc[mt][nt][r] + b1v[nt];
                *(unsigned short*)(lds + (size_t)(row0 + r) * 272 + col * 2) =
                    (unsigned short)f2bf(v);
            }
        }
    __syncthreads();

    {
        int row = t >> 1, half = t & 1;
        const char* src = lds + (size_t)row * 272 + half * 128;
        unsigned short* dst = P1 + ((size_t)(b * NN + j0 + row)) * C1 + half * 64;
        #pragma unroll
        for (int i = 0; i < 8; ++i)
            *(uint4*)(dst + i * 8) = *(const uint4*)(src + i * 16);
    }
}

// ---------------------------------------------------------------------------
// K3: fused gather + layer1 xy-term + silu + MFMA layer2 + silu + mean.
// r13: REVERT the kb-outer/#pragma-unroll-1 MFMA loop (r12's FETCH 256MB /
// WRITE 136MB regression was bfr[ntl][kb] runtime-indexing -> scratch spill;
// rule #20). Back to r10's fully-static afr[2][4] + unrolled loops. KEEPS the
// r11 pack-kernel elimination (W2 frag8 direct: shared 128KB, L2-hit).
// ---------------------------------------------------------------------------
__global__ __launch_bounds__(256) void fused2_kernel(const float* __restrict__ xyz,
                                                     const float* __restrict__ W1,
                                                     const float* __restrict__ W2,
                                                     const float* __restrict__ b2,
                                                     const unsigned short* __restrict__ P1,
                                                     const int* __restrict__ idx_ws,
                                                     float* __restrict__ tmp) {
    __shared__ __align__(16) unsigned short H1s[2][NS * C1];   // 2 x 8 KB
    __shared__ int   idxs[CPB][NS];
    __shared__ float dxs[CPB][NS], dys[CPB][NS];
    __shared__ float w1xy[C1][2];

    const int t = threadIdx.x;
    const int w = t >> 6, l = t & 63;
    const int gc0 = blockIdx.x * CPB;
    const int b   = gc0 >> 10;             // CPB divides 1024: block-uniform

    if (t < C1) {
        w1xy[t][0] = W1[(size_t)t * 66 + 0];
        w1xy[t][1] = W1[(size_t)t * 66 + 1];
    }
    if (t < CPB * NS) {                    // 128 threads stage idx/dx/dy
        int ci = t >> 5, kk = t & 31;
        int gc = gc0 + ci;
        int s = gc & (SS - 1);
        const float* x = xyz + (size_t)b * 2 * NN;
        const float* y = x + NN;
        int j = idx_ws[(size_t)gc * NS + kk];
        idxs[ci][kk] = j;
        dxs[ci][kk] = x[j] - x[s];
        dys[ci][kk] = y[j] - y[s];
    }

    // W2 B-fragments direct from global (same map+f2bf as old pack kernel)
    bf16x8 bfr[4][4];
    #pragma unroll
    for (int kb = 0; kb < 4; ++kb)
        #pragma unroll
        for (int ntl = 0; ntl < 4; ++ntl) {
            int o  = (w * 4 + ntl) * 16 + (l & 15);
            int c0 = kb * 32 + ((l >> 4) << 3);
            bfr[ntl][kb] = frag8(W2 + (size_t)o * C1 + c0);
        }
    float b2v[4];
    #pragma unroll
    for (int ntl = 0; ntl < 4; ++ntl) b2v[ntl] = b2[w * 64 + ntl * 16 + (l & 15)];

    __syncthreads();

    // --- loop-invariant per-thread state, hoisted ---
    const int k = t >> 3, cb = t & 7;      // staging roles: sample, c-block
    float wx[16], wy[16];
    #pragma unroll
    for (int i = 0; i < 16; ++i) {
        wx[i] = w1xy[cb * 16 + i][0];
        wy[i] = w1xy[cb * 16 + i][1];
    }
    const unsigned int swz = (unsigned)((k & 7) << 4);
    const unsigned int sa0 = ((unsigned)(k * 256 + cb * 32)) ^ swz;
    const unsigned int sa1 = ((unsigned)(k * 256 + cb * 32 + 16)) ^ swz;
    unsigned int afr_addr[2][4];
    #pragma unroll
    for (int mt = 0; mt < 2; ++mt)
        #pragma unroll
        for (int kb = 0; kb < 4; ++kb) {
            int m = mt * 16 + (l & 15);
            afr_addr[mt][kb] = ((unsigned)(m * 256 + kb * 64 + ((l >> 4) << 4)))
                               ^ ((unsigned)((m & 7) << 4));
        }
    const unsigned short* P1b = P1 + (size_t)b * NN * C1 + cb * 16;

    // --- software-pipelined center loop: ci=-1 primes buf0 ---
    for (int ci = -1; ci < CPB; ++ci) {
        const bool have = (ci + 1 < CPB);

        // phase 1: issue next center's gather (latency hidden under phase 2)
        uint4 q0, q1; float dx = 0.0f, dy = 0.0f;
        if (have) {
            int j = idxs[ci + 1][k];
            dx = dxs[ci + 1][k]; dy = dys[ci + 1][k];
            const uint4* pr = (const uint4*)(P1b + (size_t)j * C1);
            q0 = pr[0]; q1 = pr[1];
        }

        // phase 2: MFMA + epilogue for current center from buf[ci&1]
        // (fully static indexing — r10-verified structure)
        if (ci >= 0) {
            const char* bufr = (const char*)H1s[ci & 1];
            bf16x8 afr[2][4];
            #pragma unroll
            for (int mt = 0; mt < 2; ++mt)
                #pragma unroll
                for (int kb = 0; kb < 4; ++kb)
                    afr[mt][kb] = *(const bf16x8*)(bufr + afr_addr[mt][kb]);
            f32x4 acc[2][4];
            #pragma unroll
            for (int mt = 0; mt < 2; ++mt)
                #pragma unroll
                for (int ntl = 0; ntl < 4; ++ntl) {
                    f32x4 z4 = {0.0f, 0.0f, 0.0f, 0.0f};
                    acc[mt][ntl] = z4;
                }
            #pragma unroll
            for (int kb = 0; kb < 4; ++kb)
                #pragma unroll
                for (int mt = 0; mt < 2; ++mt)
                    #pragma unroll
                    for (int ntl = 0; ntl < 4; ++ntl)
                        acc[mt][ntl] = __builtin_amdgcn_mfma_f32_16x16x32_bf16(
                            afr[mt][kb], bfr[ntl][kb], acc[mt][ntl], 0, 0, 0);
            float po[4];
            #pragma unroll
            for (int ntl = 0; ntl < 4; ++ntl) {
                float sum = 0.0f;
                #pragma unroll
                for (int mt = 0; mt < 2; ++mt)
                    #pragma unroll
                    for (int r = 0; r < 4; ++r)
                        sum += silu_f(acc[mt][ntl][r] + b2v[ntl]);
                sum += __shfl_xor(sum, 16);
                sum += __shfl_xor(sum, 32);
                po[ntl] = sum * (1.0f / 32.0f);
            }
            if (l < 16) {
                int gc = gc0 + ci;
                #pragma unroll
                for (int ntl = 0; ntl < 4; ++ntl)
                    tmp[(size_t)gc * C2 + w * 64 + ntl * 16 + l] = po[ntl];
            }
        }

        // phase 3: silu + pack + LDS write for next center into buf[(ci+1)&1]
        if (have) {
            float hv[16];
            hv[0]  = bfl(q0.x); hv[1]  = bfh(q0.x);
            hv[2]  = bfl(q0.y); hv[3]  = bfh(q0.y);
            hv[4]  = bfl(q0.z); hv[5]  = bfh(q0.z);
            hv[6]  = bfl(q0.w); hv[7]  = bfh(q0.w);
            hv[8]  = bfl(q1.x); hv[9]  = bfh(q1.x);
            hv[10] = bfl(q1.y); hv[11] = bfh(q1.y);
            hv[12] = bfl(q1.z); hv[13] = bfh(q1.z);
            hv[14] = bfl(q1.w); hv[15] = bfh(q1.w);
            #pragma unroll
            for (int i = 0; i < 16; ++i) {
                float v = hv[i] + wx[i] * dx + wy[i] * dy;
                hv[i] = silu_f(v);
            }
            unsigned int up[8];
            #pragma unroll
            for (int q = 0; q < 8; ++q)
                up[q] = f2bf(hv[2 * q]) | (f2bf(hv[2 * q + 1]) << 16);
            char* bufw = (char*)H1s[(ci + 1) & 1];
            *(uint4*)(bufw + sa0) = make_uint4(up[0], up[1], up[2], up[3]);
            *(uint4*)(bufw + sa1) = make_uint4(up[4], up[5], up[6], up[7]);
        }
        __syncthreads();
    }
}

// ---------------------------------------------------------------------------
// K4: transpose tmp[b][s][o] -> out[b][o][s]. (UNCHANGED.)
// ---------------------------------------------------------------------------
__global__ __launch_bounds__(256) void transpose_kernel(const float* __restrict__ tmp,
                                                        float* __restrict__ out) {
    __shared__ float tile[32][33];
    int bid = blockIdx.x;
    int b  = bid >> 8;
    int r  = bid & 255;
    int s0 = (r >> 3) << 5;
    int o0 = (r & 7) << 5;
    int t = threadIdx.x;
    int c = t & 31, rr = t >> 5;
    const float* tb = tmp + (size_t)b * SS * C2;
    #pragma unroll
    for (int i = 0; i < 4; ++i) {
        int row = rr + i * 8;
        tile[row][c] = tb[(size_t)(s0 + row) * C2 + o0 + c];
    }
    __syncthreads();
    float* ob = out + (size_t)b * C2 * SS;
    #pragma unroll
    for (int i = 0; i < 4; ++i) {
        int row = rr + i * 8;
        ob[(size_t)(o0 + row) * SS + s0 + c] = tile[c][row];
    }
}

// ---------------------------------------------------------------------------
extern "C" void kernel_launch(void* const* d_in, const int* in_sizes, int n_in,
                              void* d_out, int out_size, void* d_ws, size_t ws_size,
                              hipStream_t stream) {
    const float* xyz    = (const float*)d_in[0];
    const float* points = (const float*)d_in[1];
    const float* W1     = (const float*)d_in[2];
    const float* b1     = (const float*)d_in[3];
    const float* W2     = (const float*)d_in[4];
    const float* b2     = (const float*)d_in[5];
    float* out = (float*)d_out;

    // workspace layout (total ~26.2 MB; r5-r12 passes prove ws >= 34.55 MB):
    //   idx : 1 MB    (offset 0)
    //   P1  : 16.8 MB (bf16)
    //   tmp : 8.4 MB  (f32 [b][s][o])
    const size_t OFF_P1  = (size_t)BB * SS * NS * sizeof(int);
    const size_t OFF_TMP = OFF_P1 + (size_t)BB * NN * C1 * sizeof(unsigned short);

    int*            idx = (int*)d_ws;
    unsigned short* P1  = (unsigned short*)((char*)d_ws + OFF_P1);
    float*          tmp = (float*)((char*)d_ws + OFF_TMP);

    qbp_kernel   <<<BB * SS / 4,     256, 0, stream>>>(xyz, idx);
    p1g_kernel   <<<BB * (NN / 128), 256, 0, stream>>>(points, W1, b1, P1);
    fused2_kernel<<<BB * SS / CPB,   256, 0, stream>>>(xyz, W1, W2, b2, P1, idx, tmp);
    transpose_kernel<<<BB * (SS / 32) * (C2 / 32), 256, 0, stream>>>(tmp, out);
}